// Round 4
// baseline (385.947 us; speedup 1.0000x reference)
//
#include <hip/hip_runtime.h>
#include <hip/hip_bf16.h>
#include <stdint.h>

// dims (fixed by the problem)
#define T_TOK 4096
#define NE    8
#define DM    1024
#define FF    4096
#define CAP   1536

typedef __attribute__((ext_vector_type(8))) __bf16 bf16x8;
typedef __attribute__((ext_vector_type(4))) float  f32x4;

__device__ __forceinline__ void gload_lds16(const void* gptr, void* lptr) {
  __builtin_amdgcn_global_load_lds(
      (__attribute__((address_space(1))) void*)(uintptr_t)gptr,
      (__attribute__((address_space(3))) void*)(uintptr_t)lptr,
      16, 0, 0);
}

// ---------------- small prep kernels ----------------

__global__ void conv_x_kernel(const float4* __restrict__ src, ushort4* __restrict__ dst, int n4) {
  int i = blockIdx.x * blockDim.x + threadIdx.x;
  if (i >= n4) return;
  float4 v = src[i];
  ushort4 o;
  o.x = __builtin_bit_cast(unsigned short, __float2bfloat16(v.x));
  o.y = __builtin_bit_cast(unsigned short, __float2bfloat16(v.y));
  o.z = __builtin_bit_cast(unsigned short, __float2bfloat16(v.z));
  o.w = __builtin_bit_cast(unsigned short, __float2bfloat16(v.w));
  dst[i] = o;
}

// transpose+convert: src f32 [B][R][C] -> dst bf16 [B][C][R]
__global__ __launch_bounds__(256)
void tconv_kernel(const float* __restrict__ src, __hip_bfloat16* __restrict__ dst,
                  int R, int C) {
  __shared__ float tile[64][65];
  const int b  = blockIdx.z;
  const int r0 = blockIdx.y * 64;
  const int c0 = blockIdx.x * 64;
  const float* s = src + (size_t)b * R * C;
  __hip_bfloat16* d = dst + (size_t)b * R * C;
  const int tid = threadIdx.x;
  const int tx = tid & 63, ty = tid >> 6;
#pragma unroll
  for (int rr = ty; rr < 64; rr += 4)
    tile[rr][tx] = s[(size_t)(r0 + rr) * C + c0 + tx];
  __syncthreads();
  const int lg = tid & 15;
  const int cg = tid >> 4;
#pragma unroll
  for (int w = 0; w < 4; ++w) {
    const int cc = w * 16 + cg;
    const int r4 = lg * 4;
    ushort4 o;
    o.x = __builtin_bit_cast(unsigned short, __float2bfloat16(tile[r4 + 0][cc]));
    o.y = __builtin_bit_cast(unsigned short, __float2bfloat16(tile[r4 + 1][cc]));
    o.z = __builtin_bit_cast(unsigned short, __float2bfloat16(tile[r4 + 2][cc]));
    o.w = __builtin_bit_cast(unsigned short, __float2bfloat16(tile[r4 + 3][cc]));
    *(ushort4*)&d[(size_t)(c0 + cc) * R + r0 + r4] = o;
  }
}

__global__ void router_kernel(const float* __restrict__ rw, int* __restrict__ counts,
                              int* __restrict__ tok_ids, float* __restrict__ gains) {
  int t = blockIdx.x * blockDim.x + threadIdx.x;
  if (t >= T_TOK) return;
#pragma unroll
  for (int e = 0; e < NE; ++e) {
    float w = rw[t * NE + e];
    if (w > 0.f) {
      int pos = atomicAdd(&counts[e], 1);
      if (pos < CAP) {
        tok_ids[e * CAP + pos] = t;
        gains[e * CAP + pos]   = w;
      }
    }
  }
}

__global__ void pad_kernel(const int* __restrict__ counts, int* __restrict__ tok_ids,
                           float* __restrict__ gains) {
  int i = blockIdx.x * blockDim.x + threadIdx.x;
  if (i >= NE * CAP) return;
  int e = i / CAP, pos = i % CAP;
  int ne = min(counts[e], CAP);
  if (pos >= ne) { tok_ids[i] = 0; gains[i] = 0.f; }
}

// -------- 256x256 grouped MFMA GEMM: minimum-2-phase with counted vmcnt --------
// BM=BN=256, BK=64, 512 threads (8 waves, 2M x 4N), per-wave 128x64 out.
// LDS 128KB: A[2][256r][128B], B[2][256r][128B]; XOR swizzle granule^=(row&7)
// applied on pre-swizzled GLOBAL source + read address (both-sides involution).
// Per K-tile: STAGE(next buf, 8 gload_lds) -> vmcnt(8) [waits PREV tile only,
// this tile's loads stay in flight a full iteration] -> barrier -> 24 ds_read +
// 64 MFMA (compiler-scheduled fine lgkmcnt) -> barrier. Never drain vmcnt(0)
// in-loop (T3/T4 minimum recipe).

template <int PASS>
__global__ __launch_bounds__(512, 2)
void moe_gemm2(const __hip_bfloat16* __restrict__ Asrc,
               const __hip_bfloat16* __restrict__ Bsrc,   // [E][NP][K] (B^T, k contiguous)
               const float* __restrict__ bias,            // [E][NP]
               const int* __restrict__ counts,
               const int* __restrict__ tok_ids,
               const float* __restrict__ gains,
               __hip_bfloat16* __restrict__ Hout,         // PASS1 out [E][CAP][FF]
               float* __restrict__ y)                     // PASS2 out [T][DM]
{
  constexpr int K   = (PASS == 1) ? DM : FF;
  constexpr int NP  = (PASS == 1) ? FF : DM;
  constexpr int MT  = CAP / 256;          // 6
  constexpr int NT  = NP / 256;           // 16 / 4
  constexpr int SK  = (PASS == 1) ? 1 : 2;
  constexpr int NWG = NE * MT * NT * SK;  // 768 / 384 (both %8==0)
  constexpr int KP  = K / SK;             // K per split
  constexpr int KT  = KP / 64;            // 16 / 32 K-tiles

  // XCD-aware bijective swizzle (NWG % 8 == 0); mt fastest -> B panel L2 reuse
  const int id = (blockIdx.x & 7) * (NWG / 8) + (blockIdx.x >> 3);
  const int e  = id / (MT * NT * SK);
  int r        = id % (MT * NT * SK);
  const int sp = r / (MT * NT);
  r            = r % (MT * NT);
  const int nt = r / MT;
  const int mt = r % MT;

  const int Ne = min(counts[e], CAP);
  const int m0 = mt * 256;
  if (m0 >= Ne) return;
  const int n0 = nt * 256;
  const int k0 = sp * KP;

  __shared__ alignas(128) char LDSmem[131072];  // A0@0 A1@32K B0@64K B1@96K

  const int tid  = threadIdx.x;
  const int lane = tid & 63;
  const int wid  = tid >> 6;
  const int wm   = wid >> 2;     // 0..1
  const int wn   = wid & 3;      // 0..3
  const int fr   = lane & 15;
  const int fq   = lane >> 4;    // 0..3

  // ---- staging: instr i covers rows [i*64, i*64+64); thread row = i*64 + (tid>>3)
  const int sr  = tid >> 3;
  const int ksw = ((tid & 7) ^ (sr & 7)) << 4;   // pre-swizzled source byte offset

  const char *aP[4], *bP[4];
#pragma unroll
  for (int i = 0; i < 4; ++i) {
    const int row = i * 64 + sr;
    if (PASS == 1) {
      const int tok = tok_ids[e * CAP + m0 + row];
      aP[i] = (const char*)Asrc + ((size_t)tok * DM + k0) * 2 + ksw;
    } else {
      aP[i] = (const char*)Asrc + (((size_t)e * CAP + m0 + row) * FF + k0) * 2 + ksw;
    }
    bP[i] = (const char*)Bsrc + (((size_t)e * NP + n0 + row) * K + k0) * 2 + ksw;
  }

  // ---- read bases: fragment row = 16*m + fr -> row&7 == fr&7 (swizzle-compatible)
  const int kz0 = ((fq) ^ (fr & 7)) << 4;        // k-slice 0 granule
  const int kz1 = ((4 + fq) ^ (fr & 7)) << 4;    // k-slice 1 granule
  const char* rdA = LDSmem + wm * 16384 + fr * 128;
  const char* rdB = LDSmem + 65536 + wn * 8192 + fr * 128;

  f32x4 acc[8][4] = {};

#define STAGE(d, kt) do {                                                       \
    _Pragma("unroll") for (int i = 0; i < 4; ++i)                               \
      gload_lds16(aP[i] + (kt) * 128, LDSmem + (d) * 32768 + i * 8192 + tid * 16); \
    _Pragma("unroll") for (int i = 0; i < 4; ++i)                               \
      gload_lds16(bP[i] + (kt) * 128, LDSmem + 65536 + (d) * 32768 + i * 8192 + tid * 16); \
  } while (0)

#define COMPUTE(d) do {                                                         \
    __builtin_amdgcn_s_setprio(1);                                              \
    _Pragma("unroll") for (int s = 0; s < 2; ++s) {                             \
      const int kz = s ? kz1 : kz0;                                             \
      bf16x8 bfr[4];                                                            \
      _Pragma("unroll") for (int nj = 0; nj < 4; ++nj)                          \
        bfr[nj] = *(const bf16x8*)(rdB + (d) * 32768 + nj * 2048 + kz);         \
      _Pragma("unroll") for (int mi = 0; mi < 8; ++mi) {                        \
        bf16x8 af = *(const bf16x8*)(rdA + (d) * 32768 + mi * 2048 + kz);       \
        _Pragma("unroll") for (int nj = 0; nj < 4; ++nj)                        \
          acc[mi][nj] = __builtin_amdgcn_mfma_f32_16x16x32_bf16(                \
              af, bfr[nj], acc[mi][nj], 0, 0, 0);                               \
      }                                                                         \
    }                                                                           \
    __builtin_amdgcn_s_setprio(0);                                              \
  } while (0)

  STAGE(0, 0);
  int cur = 0;
#pragma unroll 1
  for (int t = 0; t < KT - 1; ++t) {
    STAGE(cur ^ 1, t + 1);                              // next tile in flight
    asm volatile("s_waitcnt vmcnt(8)" ::: "memory");    // wait PREV tile only
    __builtin_amdgcn_s_barrier();
    __builtin_amdgcn_sched_barrier(0);
    COMPUTE(cur);
    __builtin_amdgcn_sched_barrier(0);
    __builtin_amdgcn_s_barrier();                       // readers done before overwrite
    cur ^= 1;
  }
  asm volatile("s_waitcnt vmcnt(0)" ::: "memory");
  __builtin_amdgcn_s_barrier();
  __builtin_amdgcn_sched_barrier(0);
  COMPUTE(cur);

#undef STAGE
#undef COMPUTE

  // ---- epilogue ----
  if (PASS == 1) {
#pragma unroll
    for (int nj = 0; nj < 4; ++nj) {
      const int col = n0 + wn * 64 + nj * 16 + fr;
      const float bv = bias[e * NP + col];
#pragma unroll
      for (int mi = 0; mi < 8; ++mi)
#pragma unroll
        for (int rr = 0; rr < 4; ++rr) {
          const int row = m0 + wm * 128 + mi * 16 + fq * 4 + rr;
          float v = acc[mi][nj][rr] + bv;
          Hout[((size_t)e * CAP + row) * FF + col] = __float2bfloat16(v > 0.f ? v : 0.f);
        }
    }
  } else {
    float bv[4];
#pragma unroll
    for (int nj = 0; nj < 4; ++nj)
      bv[nj] = (sp == 0) ? bias[e * NP + n0 + wn * 64 + nj * 16 + fr] : 0.f;
#pragma unroll
    for (int mi = 0; mi < 8; ++mi)
#pragma unroll
      for (int rr = 0; rr < 4; ++rr) {
        const int row  = m0 + wm * 128 + mi * 16 + fq * 4 + rr;
        const int slot = e * CAP + row;
        const float g  = gains[slot];
        if (g != 0.f) {
          const int tok = tok_ids[slot];
          float* yrow = y + (size_t)tok * DM + n0 + wn * 64 + fr;
#pragma unroll
          for (int nj = 0; nj < 4; ++nj)
            atomicAdd(yrow + nj * 16, (acc[mi][nj][rr] + bv[nj]) * g);
        }
      }
  }
}

// ---------------- launch ----------------

extern "C" void kernel_launch(void* const* d_in, const int* in_sizes, int n_in,
                              void* d_out, int out_size, void* d_ws, size_t ws_size,
                              hipStream_t stream) {
  const float* x  = (const float*)d_in[0];
  // d_in[1] = route_mask (bool) — unused: mask == (route_weight > 0)
  const float* rw = (const float*)d_in[2];
  const float* W1 = (const float*)d_in[3];
  const float* b1 = (const float*)d_in[4];
  const float* W2 = (const float*)d_in[5];
  const float* b2 = (const float*)d_in[6];
  float* y = (float*)d_out;

  char* ws = (char*)d_ws;
  size_t off = 0;
  auto alloc = [&](size_t bytes) {
    void* p = ws + off;
    off = (off + bytes + 255) & ~(size_t)255;
    return p;
  };
  __hip_bfloat16* xb  = (__hip_bfloat16*)alloc((size_t)T_TOK * DM * 2);       // 8.4 MB
  __hip_bfloat16* w1t = (__hip_bfloat16*)alloc((size_t)NE * DM * FF * 2);     // 67 MB  [E][F][D]
  __hip_bfloat16* w2t = (__hip_bfloat16*)alloc((size_t)NE * FF * DM * 2);     // 67 MB  [E][D][F]
  __hip_bfloat16* Hb  = (__hip_bfloat16*)alloc((size_t)NE * CAP * FF * 2);    // 100 MB [E][CAP][F]
  int*   counts  = (int*)alloc(NE * sizeof(int));
  int*   tok_ids = (int*)alloc((size_t)NE * CAP * sizeof(int));
  float* gains   = (float*)alloc((size_t)NE * CAP * sizeof(float));
  (void)ws_size; (void)in_sizes; (void)n_in; (void)out_size;

  hipMemsetAsync(y, 0, (size_t)T_TOK * DM * sizeof(float), stream);
  hipMemsetAsync(counts, 0, NE * sizeof(int), stream);

  conv_x_kernel<<<(T_TOK * DM / 4 + 255) / 256, 256, 0, stream>>>(
      (const float4*)x, (ushort4*)xb, T_TOK * DM / 4);
  tconv_kernel<<<dim3(FF / 64, DM / 64, NE), 256, 0, stream>>>(W1, w1t, DM, FF);
  tconv_kernel<<<dim3(DM / 64, FF / 64, NE), 256, 0, stream>>>(W2, w2t, FF, DM);
  router_kernel<<<(T_TOK + 255) / 256, 256, 0, stream>>>(rw, counts, tok_ids, gains);
  pad_kernel<<<(NE * CAP + 255) / 256, 256, 0, stream>>>(counts, tok_ids, gains);

  moe_gemm2<1><<<NE * (CAP / 256) * (FF / 256), 512, 0, stream>>>(
      xb, w1t, b1, counts, tok_ids, gains, Hb, nullptr);
  moe_gemm2<2><<<NE * (CAP / 256) * (DM / 256) * 2, 512, 0, stream>>>(
      Hb, w2t, b2, counts, tok_ids, gains, nullptr, y);
}